// Round 7
// baseline (471.372 us; speedup 1.0000x reference)
//
#include <hip/hip_runtime.h>

// Causal self-attention, B=2 T=4096 C=768 H=12 D=64.
// Pipeline: cvt x->bf16 | transpose+cvt W_attn,W_proj | QKV GEMM (bf16 MFMA,
//           v written pre-transposed) | flash attention (causal, dbuf) | proj GEMM.

#define TSEQ 4096
#define NH   12
#define HD   64
#define CEMB 768

typedef __attribute__((ext_vector_type(8))) short s8v;
typedef __attribute__((ext_vector_type(4))) float f32x4;

__device__ __forceinline__ ushort f2bf(float f) {
  union { float f; unsigned u; } x; x.f = f;
  unsigned u = x.u;
  u += 0x7fffu + ((u >> 16) & 1);   // round-to-nearest-even
  return (ushort)(u >> 16);
}

__device__ __forceinline__ void gload16(const void* gsrc, void* ldst) {
  __builtin_amdgcn_global_load_lds(
      (const __attribute__((address_space(1))) unsigned int*)gsrc,
      (__attribute__((address_space(3))) unsigned int*)ldst, 16, 0, 0);
}

// ---------------- x f32 -> bf16 ----------------
__global__ void cvt_x_kernel(const float* __restrict__ x, ushort* __restrict__ xb, int n4) {
  int i = blockIdx.x * blockDim.x + threadIdx.x;
  const int stride = gridDim.x * blockDim.x;
  for (; i < n4; i += stride) {
    float4 v = ((const float4*)x)[i];
    ushort4 o;
    o.x = f2bf(v.x); o.y = f2bf(v.y); o.z = f2bf(v.z); o.w = f2bf(v.w);
    ((ushort4*)xb)[i] = o;
  }
}

// ---------------- W[R][Cn] f32 -> WT[Cn][R] bf16 ----------------
__global__ void transpose_cvt_kernel(const float* __restrict__ W, ushort* __restrict__ WT,
                                     int R, int Cn) {
  __shared__ ushort tile[32][33];
  const int bx = blockIdx.x * 32;   // Cn dim
  const int by = blockIdx.y * 32;   // R dim
  const int tx = threadIdx.x;       // 0..31
  const int ty = threadIdx.y;       // 0..7
#pragma unroll
  for (int i = ty; i < 32; i += 8)
    tile[i][tx] = f2bf(W[(size_t)(by + i) * Cn + bx + tx]);
  __syncthreads();
#pragma unroll
  for (int i = ty; i < 32; i += 8)
    WT[(size_t)(bx + i) * R + by + tx] = tile[tx][i];
}

// ---------------- 128x128 bf16 MFMA GEMM, BK=32, 4 waves ----------------
// EPI==0: split epilogue -> k/q [bh][t][d] bf16 (q scaled), v -> vT [bh][d][t].
// EPI==1: f32 out + bias.
#define QSC 0.18033688011112042f   // 0.125 * log2(e)

template <int EPI>
__global__ void gemm128_kernel(const ushort* __restrict__ A, const ushort* __restrict__ Bt,
                               const float* __restrict__ bias,
                               ushort* __restrict__ oq, ushort* __restrict__ ok,
                               ushort* __restrict__ ovT, float* __restrict__ fout,
                               int Ktot) {
  __shared__ ushort lA[128 * 32];
  __shared__ ushort lB[128 * 32];
  const int tid = threadIdx.x;
  const int bm = blockIdx.x, bn = blockIdx.y;
  const int wid = tid >> 6, lane = tid & 63;
  const int wr = wid >> 1, wc = wid & 1;
  const int lr = lane & 15, hi = lane >> 4;

  const f32x4 fzero = {0.f, 0.f, 0.f, 0.f};
  f32x4 acc[4][4];
#pragma unroll
  for (int m = 0; m < 4; ++m)
#pragma unroll
    for (int n = 0; n < 4; ++n) acc[m][n] = fzero;

  const int g0 = tid, g1 = tid + 256;
  const int rA0 = bm * 128 + (g0 >> 2), kO0 = (g0 & 3) * 8;
  const int rA1 = bm * 128 + (g1 >> 2), kO1 = (g1 & 3) * 8;
  const int rB0 = bn * 128 + (g0 >> 2);
  const int rB1 = bn * 128 + (g1 >> 2);

  for (int kt = 0; kt < Ktot; kt += 32) {
    __syncthreads();
    gload16(A + (size_t)rA0 * Ktot + kt + kO0, &lA[g0 * 8]);
    gload16(A + (size_t)rA1 * Ktot + kt + kO1, &lA[g1 * 8]);
    gload16(Bt + (size_t)rB0 * Ktot + kt + kO0, &lB[g0 * 8]);
    gload16(Bt + (size_t)rB1 * Ktot + kt + kO1, &lB[g1 * 8]);
    __syncthreads();
    s8v av[4], bv[4];
#pragma unroll
    for (int m = 0; m < 4; ++m)
      av[m] = *(const s8v*)&lA[(wr * 64 + m * 16 + lr) * 32 + hi * 8];
#pragma unroll
    for (int n = 0; n < 4; ++n)
      bv[n] = *(const s8v*)&lB[(wc * 64 + n * 16 + lr) * 32 + hi * 8];
#pragma unroll
    for (int m = 0; m < 4; ++m)
#pragma unroll
      for (int n = 0; n < 4; ++n)
        acc[m][n] = __builtin_amdgcn_mfma_f32_16x16x32_bf16(av[m], bv[n], acc[m][n], 0, 0, 0);
  }

  if (EPI == 0) {
    const int which = bn / 6;  // 0:k 1:q 2:v (reference split order k,q,v)
#pragma unroll
    for (int n = 0; n < 4; ++n) {
      const int col = bn * 128 + wc * 64 + n * 16 + lr;
      const float bsv = bias[col];
      const int c = col - which * CEMB;
      const int h = c >> 6, d = c & 63;
#pragma unroll
      for (int m = 0; m < 4; ++m) {
        const int row0 = bm * 128 + wr * 64 + m * 16 + hi * 4;
        const int b = row0 >> 12, t0 = row0 & 4095;
        if (which == 2) {
          // vT[bh][d][t]: 4 consecutive t -> one 8B store
          uint2 w;
          w.x = (uint)f2bf(acc[m][n][0] + bsv) | ((uint)f2bf(acc[m][n][1] + bsv) << 16);
          w.y = (uint)f2bf(acc[m][n][2] + bsv) | ((uint)f2bf(acc[m][n][3] + bsv) << 16);
          *(uint2*)(ovT + ((size_t)(b * NH + h) * HD + d) * TSEQ + t0) = w;
        } else {
#pragma unroll
          for (int r = 0; r < 4; ++r) {
            const float val = acc[m][n][r] + bsv;
            const size_t idx = ((size_t)(b * NH + h) * TSEQ + t0 + r) * HD + d;
            if (which == 0) ok[idx] = f2bf(val);
            else            oq[idx] = f2bf(val * QSC);
          }
        }
      }
    }
  } else {
#pragma unroll
    for (int n = 0; n < 4; ++n) {
      const int col = bn * 128 + wc * 64 + n * 16 + lr;
      const float bsv = bias[col];
#pragma unroll
      for (int m = 0; m < 4; ++m) {
        const int row0 = bm * 128 + wr * 64 + m * 16 + hi * 4;
#pragma unroll
        for (int r = 0; r < 4; ++r)
          fout[(size_t)(row0 + r) * CEMB + col] = acc[m][n][r] + bsv;
      }
    }
  }
}

// ---------------- flash attention, causal, block-cooperative, dbuf ----------------
// Round-5 structure (uniform pacing: all blocks full work per tile, nt=2*qchunk+2)
// + per-head-class qchunk permutation so the 3 co-resident blocks per CU (same
// blockIdx.x, bh+{0,8,16}) get different workloads: qchunk=(jj+11*(bh>>3))%32.
// KV tiles of 64 double-buffered in LDS, XOR-swizzled both-sides.
// Swapped QK^T: st = mfma(K,Q): lane q=lr, kv=kvf*16+hi*4+r.
// P staged via per-wave swizzled LDS (cvt_pk pack, ds_write_b64 -> ds_read_b128).
// PV: ot = mfma(V^T, P^T): lane q=lr, d=df*16+hi*4+r.
__global__ void attn_kernel(const ushort* __restrict__ qb, const ushort* __restrict__ kb,
                            const ushort* __restrict__ vT, ushort* __restrict__ ao) {
  __shared__ ushort lK[2][4096];  // 8KB per buf
  __shared__ ushort lV[2][4096];  // 8KB per buf
  __shared__ ushort lP[4][2048];  // per-wave 32q x 64kv bf16, swizzled

  const int bh = blockIdx.y;
  const int b = bh / NH, h = bh % NH;
  const int tid = threadIdx.x;
  const int wid = tid >> 6, lane = tid & 63;
  const int lr = lane & 15, hi = lane >> 4;
  const int jj = gridDim.x - 1 - blockIdx.x;          // heavy-first within class
  const int qchunk = (jj + 11 * (bh >> 3)) & 31;      // per-CU workload mix
  const int wq = qchunk * 128 + wid * 32;             // wave's first q row

  // Q fragments: qfr[qf][kh], q row = wq+qf*16+lr, d = kh*32+hi*8..
  const ushort* qpb = qb + ((size_t)bh * TSEQ) * HD;
  s8v qfr[2][2];
#pragma unroll
  for (int qf = 0; qf < 2; ++qf)
#pragma unroll
    for (int kh = 0; kh < 2; ++kh)
      qfr[qf][kh] = *(const s8v*)(qpb + (size_t)(wq + qf * 16 + lr) * HD + kh * 32 + hi * 8);

  const ushort* kpb = kb + (size_t)bh * TSEQ * HD;
  const ushort* vtb = vT + (size_t)bh * HD * TSEQ;

  const f32x4 fzero = {0.f, 0.f, 0.f, 0.f};
  f32x4 ot[4][2];
#pragma unroll
  for (int df = 0; df < 4; ++df)
#pragma unroll
    for (int qf = 0; qf < 2; ++qf) ot[df][qf] = fzero;
  float m_run[2] = {-1e30f, -1e30f};
  float l_run[2] = {0.f, 0.f};

  const int nt = qchunk * 2 + 2;
  const int sgc0 = wid * 64 + lane, sgc1 = sgc0 + 256;  // this thread's 2 chunks
  const int sr0 = sgc0 >> 3, sb0 = (sgc0 & 7) ^ (sr0 & 7);
  const int sr1 = sgc1 >> 3, sb1 = (sgc1 & 7) ^ (sr1 & 7);

#define STAGE(buf, kv0)                                               \
  do {                                                                \
    gload16(kpb + (size_t)((kv0) + sr0) * HD + sb0 * 8, &lK[buf][sgc0 * 8]); \
    gload16(vtb + (size_t)sr0 * TSEQ + (kv0) + sb0 * 8, &lV[buf][sgc0 * 8]); \
    gload16(kpb + (size_t)((kv0) + sr1) * HD + sb1 * 8, &lK[buf][sgc1 * 8]); \
    gload16(vtb + (size_t)sr1 * TSEQ + (kv0) + sb1 * 8, &lV[buf][sgc1 * 8]); \
  } while (0)

// Per-qf: causal mask, online softmax, P-pack (cvt_pk) into per-wave LDS.
#define QFWORK(qf, QMIN)                                                     \
  do {                                                                       \
    if (kv0 + 63 > (QMIN)) {                                                 \
      _Pragma("unroll") for (int kvf = 0; kvf < 4; ++kvf)                    \
        _Pragma("unroll") for (int r = 0; r < 4; ++r)                        \
          if (kv0 + kvf * 16 + hi * 4 + r > (QMIN) + lr)                     \
            st[kvf][qf][r] = -1e30f;                                         \
    }                                                                        \
    float pmax = -1e30f;                                                     \
    _Pragma("unroll") for (int kvf = 0; kvf < 4; ++kvf)                      \
      _Pragma("unroll") for (int r = 0; r < 4; ++r)                          \
        pmax = fmaxf(pmax, st[kvf][qf][r]);                                  \
    pmax = fmaxf(pmax, __shfl_xor(pmax, 16));                                \
    pmax = fmaxf(pmax, __shfl_xor(pmax, 32));                                \
    const float m_new = fmaxf(m_run[qf], pmax);                              \
    const float scq = __builtin_amdgcn_exp2f(m_run[qf] - m_new);             \
    float psum = 0.f;                                                        \
    _Pragma("unroll") for (int kvf = 0; kvf < 4; ++kvf)                      \
      _Pragma("unroll") for (int r = 0; r < 4; ++r) {                        \
        const float p = __builtin_amdgcn_exp2f(st[kvf][qf][r] - m_new);      \
        st[kvf][qf][r] = p;                                                  \
        psum += p;                                                           \
      }                                                                      \
    psum += __shfl_xor(psum, 16);                                            \
    psum += __shfl_xor(psum, 32);                                            \
    l_run[qf] = l_run[qf] * scq + psum;                                      \
    m_run[qf] = m_new;                                                       \
    _Pragma("unroll") for (int df = 0; df < 4; ++df) {                       \
      ot[df][qf][0] *= scq; ot[df][qf][1] *= scq;                            \
      ot[df][qf][2] *= scq; ot[df][qf][3] *= scq;                            \
    }                                                                        \
    const int rowb = ((qf) * 16 + lr) * 128;                                 \
    _Pragma("unroll") for (int kvf = 0; kvf < 4; ++kvf) {                    \
      uint wlo, whi;                                                         \
      asm("v_cvt_pk_bf16_f32 %0, %1, %2"                                     \
          : "=v"(wlo) : "v"(st[kvf][qf][0]), "v"(st[kvf][qf][1]));           \
      asm("v_cvt_pk_bf16_f32 %0, %1, %2"                                     \
          : "=v"(whi) : "v"(st[kvf][qf][2]), "v"(st[kvf][qf][3]));           \
      uint2 w; w.x = wlo; w.y = whi;                                         \
      *(uint2*)((char*)pw + rowb + ((kvf * 32 + hi * 8) ^ sw)) = w;          \
    }                                                                        \
  } while (0)

  STAGE(0, 0);
  asm volatile("s_waitcnt vmcnt(0)" ::: "memory");
  __syncthreads();

  int cur = 0;
  const int sw = (lr & 7) << 4;
  ushort* pw = lP[wid];

  for (int t = 0; t < nt; ++t) {
    const int kv0 = t * 64;
    if (t + 1 < nt) STAGE(cur ^ 1, kv0 + 64);

    const bool act1 = (kv0 <= wq + 31);  // wave-uniform: high strip live
    const bool act0 = (kv0 <= wq + 15);  // wave-uniform: low strip live
    if (act1) {
      const char* lKb = (const char*)lK[cur];
      const char* lVb = (const char*)lV[cur];
      // ---- QK^T ----
      f32x4 st[4][2];
#pragma unroll
      for (int kvf = 0; kvf < 4; ++kvf) {
        const int row = kvf * 16 + lr;
        const s8v a0 = *(const s8v*)(lKb + row * 128 + ((hi * 16) ^ sw));
        const s8v a1 = *(const s8v*)(lKb + row * 128 + ((64 + hi * 16) ^ sw));
        f32x4 s1 = fzero;
        s1 = __builtin_amdgcn_mfma_f32_16x16x32_bf16(a0, qfr[1][0], s1, 0, 0, 0);
        s1 = __builtin_amdgcn_mfma_f32_16x16x32_bf16(a1, qfr[1][1], s1, 0, 0, 0);
        st[kvf][1] = s1;
        if (act0) {
          f32x4 s0 = fzero;
          s0 = __builtin_amdgcn_mfma_f32_16x16x32_bf16(a0, qfr[0][0], s0, 0, 0, 0);
          s0 = __builtin_amdgcn_mfma_f32_16x16x32_bf16(a1, qfr[0][1], s0, 0, 0, 0);
          st[kvf][0] = s0;
        }
      }

      // ---- softmax + P-pack per active strip ----
      QFWORK(1, wq + 16);
      if (act0) QFWORK(0, wq);

      asm volatile("s_waitcnt lgkmcnt(0)" ::: "memory");
      __builtin_amdgcn_sched_barrier(0);

      // ---- PV ----
#pragma unroll
      for (int s = 0; s < 2; ++s) {
        s8v vf[4];
#pragma unroll
        for (int df = 0; df < 4; ++df) {
          const int row = df * 16 + lr;
          vf[df] = *(const s8v*)(lVb + row * 128 + ((s * 64 + hi * 16) ^ sw));
        }
        {
          const s8v pf = *(const s8v*)((char*)pw + (16 + lr) * 128 + ((s * 64 + hi * 16) ^ sw));
#pragma unroll
          for (int df = 0; df < 4; ++df)
            ot[df][1] = __builtin_amdgcn_mfma_f32_16x16x32_bf16(vf[df], pf, ot[df][1], 0, 0, 0);
        }
        if (act0) {
          const s8v pf = *(const s8v*)((char*)pw + lr * 128 + ((s * 64 + hi * 16) ^ sw));
#pragma unroll
          for (int df = 0; df < 4; ++df)
            ot[df][0] = __builtin_amdgcn_mfma_f32_16x16x32_bf16(vf[df], pf, ot[df][0], 0, 0, 0);
        }
      }
    }

    asm volatile("s_waitcnt vmcnt(0)" ::: "memory");
    __syncthreads();
    cur ^= 1;
  }

  // ---- epilogue ----
#pragma unroll
  for (int qf = 0; qf < 2; ++qf) {
    const float inv_l = 1.f / l_run[qf];
    ushort* op = ao + ((size_t)(b * TSEQ + wq + qf * 16 + lr)) * CEMB + h * HD + hi * 4;
#pragma unroll
    for (int df = 0; df < 4; ++df) {
      ushort2 w0, w1;
      w0.x = f2bf(ot[df][qf][0] * inv_l); w0.y = f2bf(ot[df][qf][1] * inv_l);
      w1.x = f2bf(ot[df][qf][2] * inv_l); w1.y = f2bf(ot[df][qf][3] * inv_l);
      *(ushort2*)(op + df * 16) = w0;
      *(ushort2*)(op + df * 16 + 2) = w1;
    }
  }
#undef STAGE
#undef QFWORK
}

// ---------------- launch ----------------
extern "C" void kernel_launch(void* const* d_in, const int* in_sizes, int n_in,
                              void* d_out, int out_size, void* d_ws, size_t ws_size,
                              hipStream_t stream) {
  const float* x      = (const float*)d_in[0];
  const float* W_attn = (const float*)d_in[1];
  const float* b_attn = (const float*)d_in[2];
  const float* W_proj = (const float*)d_in[3];
  const float* b_proj = (const float*)d_in[4];
  float* out = (float*)d_out;

  char* ws = (char*)d_ws;
  ushort* xb  = (ushort*)(ws + 0);          // also attn_out (x dead after QKV GEMM)
  ushort* WaT = (ushort*)(ws + 12582912);
  ushort* WpT = (ushort*)(ws + 16121856);
  ushort* qbf = (ushort*)(ws + 17301504);
  ushort* kbf = (ushort*)(ws + 29884416);
  ushort* vTb = (ushort*)(ws + 55050240);

  cvt_x_kernel<<<dim3(2048), dim3(256), 0, stream>>>(x, xb, (2 * TSEQ * CEMB) / 4);
  transpose_cvt_kernel<<<dim3(72, 24), dim3(32, 8), 0, stream>>>(W_attn, WaT, CEMB, 3 * CEMB);
  transpose_cvt_kernel<<<dim3(24, 24), dim3(32, 8), 0, stream>>>(W_proj, WpT, CEMB, CEMB);
  gemm128_kernel<0><<<dim3(64, 18), dim3(256), 0, stream>>>(xb, WaT, b_attn,
                                                            qbf, kbf, vTb, nullptr, CEMB);
  attn_kernel<<<dim3(32, 24), dim3(256), 0, stream>>>(qbf, kbf, vTb, xb);
  gemm128_kernel<1><<<dim3(64, 6), dim3(256), 0, stream>>>(xb, WpT, b_proj,
                                                           nullptr, nullptr, nullptr, out, CEMB);
}

// Round 8
// 335.647 us; speedup vs baseline: 1.4044x; 1.4044x over previous
//
#include <hip/hip_runtime.h>

// Causal self-attention, B=2 T=4096 C=768 H=12 D=64.
// Pipeline: cvt x->bf16 | transpose+cvt W_attn,W_proj | QKV GEMM (bf16 MFMA,
//           v written pre-transposed) | flash attention (causal, dbuf) | proj GEMM.
// Attn scheduling: Round-5 lockstep (qchunk = jj, uniform pacing). Both
// "balanced" variants (R6 pair-chunks, R7 per-head permutation) regressed via
// L2 thrash (WRITE_SIZE 18 -> 240+ MB); lockstep is the proven schedule.

#define TSEQ 4096
#define NH   12
#define HD   64
#define CEMB 768

typedef __attribute__((ext_vector_type(8))) short s8v;
typedef __attribute__((ext_vector_type(4))) float f32x4;

__device__ __forceinline__ ushort f2bf(float f) {
  union { float f; unsigned u; } x; x.f = f;
  unsigned u = x.u;
  u += 0x7fffu + ((u >> 16) & 1);   // round-to-nearest-even
  return (ushort)(u >> 16);
}

__device__ __forceinline__ void gload16(const void* gsrc, void* ldst) {
  __builtin_amdgcn_global_load_lds(
      (const __attribute__((address_space(1))) unsigned int*)gsrc,
      (__attribute__((address_space(3))) unsigned int*)ldst, 16, 0, 0);
}

// ---------------- x f32 -> bf16 ----------------
__global__ void cvt_x_kernel(const float* __restrict__ x, ushort* __restrict__ xb, int n4) {
  int i = blockIdx.x * blockDim.x + threadIdx.x;
  const int stride = gridDim.x * blockDim.x;
  for (; i < n4; i += stride) {
    float4 v = ((const float4*)x)[i];
    ushort4 o;
    o.x = f2bf(v.x); o.y = f2bf(v.y); o.z = f2bf(v.z); o.w = f2bf(v.w);
    ((ushort4*)xb)[i] = o;
  }
}

// ---------------- W[R][Cn] f32 -> WT[Cn][R] bf16 ----------------
__global__ void transpose_cvt_kernel(const float* __restrict__ W, ushort* __restrict__ WT,
                                     int R, int Cn) {
  __shared__ ushort tile[32][33];
  const int bx = blockIdx.x * 32;   // Cn dim
  const int by = blockIdx.y * 32;   // R dim
  const int tx = threadIdx.x;       // 0..31
  const int ty = threadIdx.y;       // 0..7
#pragma unroll
  for (int i = ty; i < 32; i += 8)
    tile[i][tx] = f2bf(W[(size_t)(by + i) * Cn + bx + tx]);
  __syncthreads();
#pragma unroll
  for (int i = ty; i < 32; i += 8)
    WT[(size_t)(bx + i) * R + by + tx] = tile[tx][i];
}

// ---------------- 128x128 bf16 MFMA GEMM, BK=32, 4 waves ----------------
// EPI==0: split epilogue -> k/q [bh][t][d] bf16 (q scaled), v -> vT [bh][d][t].
// EPI==1: f32 out + bias.
#define QSC 0.18033688011112042f   // 0.125 * log2(e)

template <int EPI>
__global__ void gemm128_kernel(const ushort* __restrict__ A, const ushort* __restrict__ Bt,
                               const float* __restrict__ bias,
                               ushort* __restrict__ oq, ushort* __restrict__ ok,
                               ushort* __restrict__ ovT, float* __restrict__ fout,
                               int Ktot) {
  __shared__ ushort lA[128 * 32];
  __shared__ ushort lB[128 * 32];
  const int tid = threadIdx.x;
  const int bm = blockIdx.x, bn = blockIdx.y;
  const int wid = tid >> 6, lane = tid & 63;
  const int wr = wid >> 1, wc = wid & 1;
  const int lr = lane & 15, hi = lane >> 4;

  const f32x4 fzero = {0.f, 0.f, 0.f, 0.f};
  f32x4 acc[4][4];
#pragma unroll
  for (int m = 0; m < 4; ++m)
#pragma unroll
    for (int n = 0; n < 4; ++n) acc[m][n] = fzero;

  const int g0 = tid, g1 = tid + 256;
  const int rA0 = bm * 128 + (g0 >> 2), kO0 = (g0 & 3) * 8;
  const int rA1 = bm * 128 + (g1 >> 2), kO1 = (g1 & 3) * 8;
  const int rB0 = bn * 128 + (g0 >> 2);
  const int rB1 = bn * 128 + (g1 >> 2);

  for (int kt = 0; kt < Ktot; kt += 32) {
    __syncthreads();
    gload16(A + (size_t)rA0 * Ktot + kt + kO0, &lA[g0 * 8]);
    gload16(A + (size_t)rA1 * Ktot + kt + kO1, &lA[g1 * 8]);
    gload16(Bt + (size_t)rB0 * Ktot + kt + kO0, &lB[g0 * 8]);
    gload16(Bt + (size_t)rB1 * Ktot + kt + kO1, &lB[g1 * 8]);
    __syncthreads();
    s8v av[4], bv[4];
#pragma unroll
    for (int m = 0; m < 4; ++m)
      av[m] = *(const s8v*)&lA[(wr * 64 + m * 16 + lr) * 32 + hi * 8];
#pragma unroll
    for (int n = 0; n < 4; ++n)
      bv[n] = *(const s8v*)&lB[(wc * 64 + n * 16 + lr) * 32 + hi * 8];
#pragma unroll
    for (int m = 0; m < 4; ++m)
#pragma unroll
      for (int n = 0; n < 4; ++n)
        acc[m][n] = __builtin_amdgcn_mfma_f32_16x16x32_bf16(av[m], bv[n], acc[m][n], 0, 0, 0);
  }

  if (EPI == 0) {
    const int which = bn / 6;  // 0:k 1:q 2:v (reference split order k,q,v)
#pragma unroll
    for (int n = 0; n < 4; ++n) {
      const int col = bn * 128 + wc * 64 + n * 16 + lr;
      const float bsv = bias[col];
      const int c = col - which * CEMB;
      const int h = c >> 6, d = c & 63;
#pragma unroll
      for (int m = 0; m < 4; ++m) {
        const int row0 = bm * 128 + wr * 64 + m * 16 + hi * 4;
        const int b = row0 >> 12, t0 = row0 & 4095;
        if (which == 2) {
          // vT[bh][d][t]: 4 consecutive t -> one 8B store
          uint2 w;
          w.x = (uint)f2bf(acc[m][n][0] + bsv) | ((uint)f2bf(acc[m][n][1] + bsv) << 16);
          w.y = (uint)f2bf(acc[m][n][2] + bsv) | ((uint)f2bf(acc[m][n][3] + bsv) << 16);
          *(uint2*)(ovT + ((size_t)(b * NH + h) * HD + d) * TSEQ + t0) = w;
        } else {
#pragma unroll
          for (int r = 0; r < 4; ++r) {
            const float val = acc[m][n][r] + bsv;
            const size_t idx = ((size_t)(b * NH + h) * TSEQ + t0 + r) * HD + d;
            if (which == 0) ok[idx] = f2bf(val);
            else            oq[idx] = f2bf(val * QSC);
          }
        }
      }
    }
  } else {
#pragma unroll
    for (int n = 0; n < 4; ++n) {
      const int col = bn * 128 + wc * 64 + n * 16 + lr;
      const float bsv = bias[col];
#pragma unroll
      for (int m = 0; m < 4; ++m) {
        const int row0 = bm * 128 + wr * 64 + m * 16 + hi * 4;
#pragma unroll
        for (int r = 0; r < 4; ++r)
          fout[(size_t)(row0 + r) * CEMB + col] = acc[m][n][r] + bsv;
      }
    }
  }
}

// ---------------- flash attention, causal, block-cooperative, dbuf ----------------
// Round-5 lockstep schedule. 4 waves/block; block owns 128 q rows (wave: 32).
// KV tiles of 64 double-buffered in LDS, XOR-swizzled both-sides.
// 2-phase pipeline: STAGE(next) | compute(cur) | vmcnt(0)+barrier.
// Swapped QK^T: st = mfma(K,Q): lane q=lr, kv=kvf*16+hi*4+r.
// P staged via per-wave swizzled LDS (cvt_pk pack, ds_write_b64 -> ds_read_b128).
// PV: ot = mfma(V^T, P^T): lane q=lr, d=df*16+hi*4+r.
__global__ void attn_kernel(const ushort* __restrict__ qb, const ushort* __restrict__ kb,
                            const ushort* __restrict__ vT, ushort* __restrict__ ao) {
  __shared__ ushort lK[2][4096];  // 8KB per buf
  __shared__ ushort lV[2][4096];  // 8KB per buf
  __shared__ ushort lP[4][2048];  // per-wave 32q x 64kv bf16, swizzled

  const int bh = blockIdx.y;
  const int b = bh / NH, h = bh % NH;
  const int tid = threadIdx.x;
  const int wid = tid >> 6, lane = tid & 63;
  const int lr = lane & 15, hi = lane >> 4;
  const int qchunk = gridDim.x - 1 - blockIdx.x;  // heavy blocks first
  const int wq = qchunk * 128 + wid * 32;         // wave's first q row

  // Q fragments: qfr[qf][kh], q row = wq+qf*16+lr, d = kh*32+hi*8..
  const ushort* qpb = qb + ((size_t)bh * TSEQ) * HD;
  s8v qfr[2][2];
#pragma unroll
  for (int qf = 0; qf < 2; ++qf)
#pragma unroll
    for (int kh = 0; kh < 2; ++kh)
      qfr[qf][kh] = *(const s8v*)(qpb + (size_t)(wq + qf * 16 + lr) * HD + kh * 32 + hi * 8);

  const ushort* kpb = kb + (size_t)bh * TSEQ * HD;
  const ushort* vtb = vT + (size_t)bh * HD * TSEQ;

  const f32x4 fzero = {0.f, 0.f, 0.f, 0.f};
  f32x4 ot[4][2];
#pragma unroll
  for (int df = 0; df < 4; ++df)
#pragma unroll
    for (int qf = 0; qf < 2; ++qf) ot[df][qf] = fzero;
  float m_run[2] = {-1e30f, -1e30f};
  float l_run[2] = {0.f, 0.f};

  const int nt = qchunk * 2 + 2;
  const int sgc0 = wid * 64 + lane, sgc1 = sgc0 + 256;  // this thread's 2 chunks
  const int sr0 = sgc0 >> 3, sb0 = (sgc0 & 7) ^ (sr0 & 7);
  const int sr1 = sgc1 >> 3, sb1 = (sgc1 & 7) ^ (sr1 & 7);

#define STAGE(buf, kv0)                                               \
  do {                                                                \
    gload16(kpb + (size_t)((kv0) + sr0) * HD + sb0 * 8, &lK[buf][sgc0 * 8]); \
    gload16(vtb + (size_t)sr0 * TSEQ + (kv0) + sb0 * 8, &lV[buf][sgc0 * 8]); \
    gload16(kpb + (size_t)((kv0) + sr1) * HD + sb1 * 8, &lK[buf][sgc1 * 8]); \
    gload16(vtb + (size_t)sr1 * TSEQ + (kv0) + sb1 * 8, &lV[buf][sgc1 * 8]); \
  } while (0)

// Per-qf: causal mask, online softmax, P-pack (cvt_pk) into per-wave LDS.
#define QFWORK(qf, QMIN)                                                     \
  do {                                                                       \
    if (kv0 + 63 > (QMIN)) {                                                 \
      _Pragma("unroll") for (int kvf = 0; kvf < 4; ++kvf)                    \
        _Pragma("unroll") for (int r = 0; r < 4; ++r)                        \
          if (kv0 + kvf * 16 + hi * 4 + r > (QMIN) + lr)                     \
            st[kvf][qf][r] = -1e30f;                                         \
    }                                                                        \
    float pmax = -1e30f;                                                     \
    _Pragma("unroll") for (int kvf = 0; kvf < 4; ++kvf)                      \
      _Pragma("unroll") for (int r = 0; r < 4; ++r)                          \
        pmax = fmaxf(pmax, st[kvf][qf][r]);                                  \
    pmax = fmaxf(pmax, __shfl_xor(pmax, 16));                                \
    pmax = fmaxf(pmax, __shfl_xor(pmax, 32));                                \
    const float m_new = fmaxf(m_run[qf], pmax);                              \
    const float scq = __builtin_amdgcn_exp2f(m_run[qf] - m_new);             \
    float psum = 0.f;                                                        \
    _Pragma("unroll") for (int kvf = 0; kvf < 4; ++kvf)                      \
      _Pragma("unroll") for (int r = 0; r < 4; ++r) {                        \
        const float p = __builtin_amdgcn_exp2f(st[kvf][qf][r] - m_new);      \
        st[kvf][qf][r] = p;                                                  \
        psum += p;                                                           \
      }                                                                      \
    psum += __shfl_xor(psum, 16);                                            \
    psum += __shfl_xor(psum, 32);                                            \
    l_run[qf] = l_run[qf] * scq + psum;                                      \
    m_run[qf] = m_new;                                                       \
    _Pragma("unroll") for (int df = 0; df < 4; ++df) {                       \
      ot[df][qf][0] *= scq; ot[df][qf][1] *= scq;                            \
      ot[df][qf][2] *= scq; ot[df][qf][3] *= scq;                            \
    }                                                                        \
    const int rowb = ((qf) * 16 + lr) * 128;                                 \
    _Pragma("unroll") for (int kvf = 0; kvf < 4; ++kvf) {                    \
      uint wlo, whi;                                                         \
      asm("v_cvt_pk_bf16_f32 %0, %1, %2"                                     \
          : "=v"(wlo) : "v"(st[kvf][qf][0]), "v"(st[kvf][qf][1]));           \
      asm("v_cvt_pk_bf16_f32 %0, %1, %2"                                     \
          : "=v"(whi) : "v"(st[kvf][qf][2]), "v"(st[kvf][qf][3]));           \
      uint2 w; w.x = wlo; w.y = whi;                                         \
      *(uint2*)((char*)pw + rowb + ((kvf * 32 + hi * 8) ^ sw)) = w;          \
    }                                                                        \
  } while (0)

  STAGE(0, 0);
  asm volatile("s_waitcnt vmcnt(0)" ::: "memory");
  __syncthreads();

  int cur = 0;
  const int sw = (lr & 7) << 4;
  ushort* pw = lP[wid];

  for (int t = 0; t < nt; ++t) {
    const int kv0 = t * 64;
    if (t + 1 < nt) STAGE(cur ^ 1, kv0 + 64);

    if (kv0 <= wq + 31) {   // not fully masked for this wave
      const char* lKb = (const char*)lK[cur];
      const char* lVb = (const char*)lV[cur];
      // ---- QK^T ----
      f32x4 st[4][2];
      __builtin_amdgcn_s_setprio(1);
#pragma unroll
      for (int kvf = 0; kvf < 4; ++kvf) {
        const int row = kvf * 16 + lr;
        const s8v a0 = *(const s8v*)(lKb + row * 128 + ((hi * 16) ^ sw));
        const s8v a1 = *(const s8v*)(lKb + row * 128 + ((64 + hi * 16) ^ sw));
#pragma unroll
        for (int qf = 0; qf < 2; ++qf) {
          f32x4 s = fzero;
          s = __builtin_amdgcn_mfma_f32_16x16x32_bf16(a0, qfr[qf][0], s, 0, 0, 0);
          s = __builtin_amdgcn_mfma_f32_16x16x32_bf16(a1, qfr[qf][1], s, 0, 0, 0);
          st[kvf][qf] = s;
        }
      }
      __builtin_amdgcn_s_setprio(0);

      // ---- softmax + P-pack per strip ----
      QFWORK(1, wq + 16);
      QFWORK(0, wq);

      asm volatile("s_waitcnt lgkmcnt(0)" ::: "memory");
      __builtin_amdgcn_sched_barrier(0);

      // ---- PV ----
      __builtin_amdgcn_s_setprio(1);
#pragma unroll
      for (int s = 0; s < 2; ++s) {
        s8v vf[4];
#pragma unroll
        for (int df = 0; df < 4; ++df) {
          const int row = df * 16 + lr;
          vf[df] = *(const s8v*)(lVb + row * 128 + ((s * 64 + hi * 16) ^ sw));
        }
#pragma unroll
        for (int qf = 0; qf < 2; ++qf) {
          const s8v pf = *(const s8v*)((char*)pw + (qf * 16 + lr) * 128 + ((s * 64 + hi * 16) ^ sw));
#pragma unroll
          for (int df = 0; df < 4; ++df)
            ot[df][qf] = __builtin_amdgcn_mfma_f32_16x16x32_bf16(vf[df], pf, ot[df][qf], 0, 0, 0);
        }
      }
      __builtin_amdgcn_s_setprio(0);
    }

    asm volatile("s_waitcnt vmcnt(0)" ::: "memory");
    __syncthreads();
    cur ^= 1;
  }

  // ---- epilogue (cvt_pk, 8B stores) ----
#pragma unroll
  for (int qf = 0; qf < 2; ++qf) {
    const float inv_l = 1.f / l_run[qf];
    ushort* op = ao + ((size_t)(b * TSEQ + wq + qf * 16 + lr)) * CEMB + h * HD + hi * 4;
#pragma unroll
    for (int df = 0; df < 4; ++df) {
      const float o0 = ot[df][qf][0] * inv_l, o1 = ot[df][qf][1] * inv_l;
      const float o2 = ot[df][qf][2] * inv_l, o3 = ot[df][qf][3] * inv_l;
      uint wlo, whi;
      asm("v_cvt_pk_bf16_f32 %0, %1, %2" : "=v"(wlo) : "v"(o0), "v"(o1));
      asm("v_cvt_pk_bf16_f32 %0, %1, %2" : "=v"(whi) : "v"(o2), "v"(o3));
      uint2 w; w.x = wlo; w.y = whi;
      *(uint2*)(op + df * 16) = w;
    }
  }
#undef STAGE
#undef QFWORK
}

// ---------------- launch ----------------
extern "C" void kernel_launch(void* const* d_in, const int* in_sizes, int n_in,
                              void* d_out, int out_size, void* d_ws, size_t ws_size,
                              hipStream_t stream) {
  const float* x      = (const float*)d_in[0];
  const float* W_attn = (const float*)d_in[1];
  const float* b_attn = (const float*)d_in[2];
  const float* W_proj = (const float*)d_in[3];
  const float* b_proj = (const float*)d_in[4];
  float* out = (float*)d_out;

  char* ws = (char*)d_ws;
  ushort* xb  = (ushort*)(ws + 0);          // also attn_out (x dead after QKV GEMM)
  ushort* WaT = (ushort*)(ws + 12582912);
  ushort* WpT = (ushort*)(ws + 16121856);
  ushort* qbf = (ushort*)(ws + 17301504);
  ushort* kbf = (ushort*)(ws + 29884416);
  ushort* vTb = (ushort*)(ws + 55050240);

  cvt_x_kernel<<<dim3(2048), dim3(256), 0, stream>>>(x, xb, (2 * TSEQ * CEMB) / 4);
  transpose_cvt_kernel<<<dim3(72, 24), dim3(32, 8), 0, stream>>>(W_attn, WaT, CEMB, 3 * CEMB);
  transpose_cvt_kernel<<<dim3(24, 24), dim3(32, 8), 0, stream>>>(W_proj, WpT, CEMB, CEMB);
  gemm128_kernel<0><<<dim3(64, 18), dim3(256), 0, stream>>>(xb, WaT, b_attn,
                                                            qbf, kbf, vTb, nullptr, CEMB);
  attn_kernel<<<dim3(32, 24), dim3(256), 0, stream>>>(qbf, kbf, vTb, xb);
  gemm128_kernel<1><<<dim3(64, 6), dim3(256), 0, stream>>>(xb, WpT, b_proj,
                                                           nullptr, nullptr, nullptr, out, CEMB);
}